// Round 5
// baseline (207.396 us; speedup 1.0000x reference)
//
#include <hip/hip_runtime.h>
#include <hip/hip_bf16.h>
#include <stdint.h>

typedef short s16x8 __attribute__((ext_vector_type(8)));
typedef float f32x4 __attribute__((ext_vector_type(4)));

static constexpr int DDIM = 256;
static constexpr int NTILE = 2080;   // 64*65/2 upper-triangle tiles
static constexpr float TEN_LOG2E = 14.4269504088896340736f; // 10 * log2(e)

// ---------------- Kernel 1: row-normalize p = [z_i; z_j], cast to bf16 ----------------
// Also zero-inits row_s[8192] (blocks 0..7) and the done-counter (block 0).
__global__ __launch_bounds__(256) void normalize_bf16_kernel(
    const float* __restrict__ zi, const float* __restrict__ zj,
    ushort* __restrict__ pn, float* __restrict__ row_s, int* __restrict__ done)
{
    if (blockIdx.x < 8) {
        ((float4*)row_s)[blockIdx.x * 256 + threadIdx.x] = (float4){0.f, 0.f, 0.f, 0.f};
        if (blockIdx.x == 0 && threadIdx.x == 0) *done = 0;
    }

    const int row  = blockIdx.x * 4 + (threadIdx.x >> 6);
    const int lane = threadIdx.x & 63;
    const float* src = (row < 4096) ? (zi + (size_t)row * DDIM)
                                    : (zj + (size_t)(row - 4096) * DDIM);
    float4 v = ((const float4*)src)[lane];
    float ss = v.x * v.x + v.y * v.y + v.z * v.z + v.w * v.w;
    #pragma unroll
    for (int off = 32; off > 0; off >>= 1) ss += __shfl_xor(ss, off, 64);
    const float inv = 1.0f / fmaxf(sqrtf(ss), 1e-8f);

    ushort4 o;
    o.x = __builtin_bit_cast(unsigned short, __float2bfloat16(v.x * inv));
    o.y = __builtin_bit_cast(unsigned short, __float2bfloat16(v.y * inv));
    o.z = __builtin_bit_cast(unsigned short, __float2bfloat16(v.z * inv));
    o.w = __builtin_bit_cast(unsigned short, __float2bfloat16(v.w * inv));
    ((ushort4*)(pn + (size_t)row * DDIM))[lane] = o;
}

// ---------------- Kernel 2: upper-triangle Gram tiles + fused finalize ----------------
// 2080 blocks, 128x128 tile each, 4 waves x (64x64 via 16x16x32 MFMA, 4x4 frags).
// No LDS/barriers in the K-loop: fragments load straight from L2-resident pn with a
// 2-deep register ping-pong (load kt+1 while MFMA kt). Last block to finish runs the
// loss finalize (agent-scope loads — per-XCD L2s are not coherent).
__global__ __launch_bounds__(256, 2) void simexp_kernel(
    const ushort* __restrict__ pn,
    float* __restrict__ row_s,
    float* __restrict__ pos_out,
    int* __restrict__ done,
    float* __restrict__ out)
{
    const int tid  = threadIdx.x;
    const int w    = tid >> 6;
    const int lane = tid & 63;
    const int q    = lane >> 4;      // 0..3: K-octet of the MFMA operand
    const int l15  = lane & 15;
    const int wm   = (w >> 1) * 64;  // wave row offset in 128x128 tile
    const int wn   = (w & 1) * 64;   // wave col offset

    // ---- upper-triangle decode: block b -> (ti, tj), ti <= tj ----
    const int b = blockIdx.x;
    int ti = (int)(64.5f - sqrtf(64.5f * 64.5f - 2.0f * (float)b));
    while ((ti + 1) * 64 - ((ti + 1) * ti) / 2 <= b) ++ti;
    while (ti * 64 - (ti * (ti - 1)) / 2 > b) --ti;
    const int tj = ti + (b - (ti * 64 - (ti * (ti - 1)) / 2));
    const int r0 = ti * 128, c0 = tj * 128;
    const bool diag  = (ti == tj);
    const bool ptile = (tj == ti + 32);  // contains positive-pair diagonal

    // per-lane fragment base pointers (16B at +kt*64B per K-step)
    const ushort* pa[4];
    const ushort* pb[4];
    #pragma unroll
    for (int mi = 0; mi < 4; ++mi)
        pa[mi] = pn + (size_t)(r0 + wm + mi * 16 + l15) * DDIM + q * 8;
    #pragma unroll
    for (int ni = 0; ni < 4; ++ni)
        pb[ni] = pn + (size_t)(c0 + wn + ni * 16 + l15) * DDIM + q * 8;

    f32x4 acc[4][4];
    #pragma unroll
    for (int mi = 0; mi < 4; ++mi)
        #pragma unroll
        for (int ni = 0; ni < 4; ++ni)
            acc[mi][ni] = (f32x4){0.f, 0.f, 0.f, 0.f};

    // ---- K-loop with 2-deep register ping-pong ----
    s16x8 af[2][4], bfr[2][4];
    #pragma unroll
    for (int mi = 0; mi < 4; ++mi) af[0][mi] = *(const s16x8*)(pa[mi]);
    #pragma unroll
    for (int ni = 0; ni < 4; ++ni) bfr[0][ni] = *(const s16x8*)(pb[ni]);

    #pragma unroll
    for (int kt = 0; kt < 8; ++kt) {
        const int cur = kt & 1, nxt = cur ^ 1;
        if (kt < 7) {
            #pragma unroll
            for (int mi = 0; mi < 4; ++mi)
                af[nxt][mi] = *(const s16x8*)(pa[mi] + (kt + 1) * 32);
            #pragma unroll
            for (int ni = 0; ni < 4; ++ni)
                bfr[nxt][ni] = *(const s16x8*)(pb[ni] + (kt + 1) * 32);
        }
        #pragma unroll
        for (int mi = 0; mi < 4; ++mi)
            #pragma unroll
            for (int ni = 0; ni < 4; ++ni)
                acc[mi][ni] = __builtin_amdgcn_mfma_f32_16x16x32_bf16(
                    af[cur][mi], bfr[cur][ni], acc[mi][ni], 0, 0, 0);
    }

    // ---- epilogue: exp, diag mask, positive extraction, row+col sums ----
    // C/D layout (16x16): col = lane&15, row = q*4 + r
    float rsum[4][4];
    float csum[4] = {0.f, 0.f, 0.f, 0.f};
    #pragma unroll
    for (int mi = 0; mi < 4; ++mi)
        #pragma unroll
        for (int r = 0; r < 4; ++r) rsum[mi][r] = 0.0f;

    #pragma unroll
    for (int mi = 0; mi < 4; ++mi)
        #pragma unroll
        for (int ni = 0; ni < 4; ++ni)
            #pragma unroll
            for (int r = 0; r < 4; ++r) {
                const int lr = wm + mi * 16 + q * 4 + r;
                const int lc = wn + ni * 16 + l15;
                float e = exp2f(acc[mi][ni][r] * TEN_LOG2E);
                if (diag && lr == lc) e = 0.0f;          // mask self-similarity
                rsum[mi][r] += e;
                csum[ni]    += e;
                if (ptile && lr == lc) {                 // positive pair: col = row + 4096
                    const float v = acc[mi][ni][r] * 10.0f;
                    __hip_atomic_store(&pos_out[r0 + lr], v, __ATOMIC_RELAXED,
                                       __HIP_MEMORY_SCOPE_AGENT);
                    __hip_atomic_store(&pos_out[c0 + lr], v, __ATOMIC_RELAXED,
                                       __HIP_MEMORY_SCOPE_AGENT);
                }
            }

    // row sums: reduce across the 16 lanes (cols) of each quad
    #pragma unroll
    for (int mi = 0; mi < 4; ++mi)
        #pragma unroll
        for (int r = 0; r < 4; ++r) {
            float v = rsum[mi][r];
            v += __shfl_xor(v, 1, 64);
            v += __shfl_xor(v, 2, 64);
            v += __shfl_xor(v, 4, 64);
            v += __shfl_xor(v, 8, 64);
            rsum[mi][r] = v;
        }
    if (l15 == 0) {
        #pragma unroll
        for (int mi = 0; mi < 4; ++mi)
            #pragma unroll
            for (int r = 0; r < 4; ++r)
                atomicAdd(&row_s[r0 + wm + mi * 16 + q * 4 + r], rsum[mi][r]);
    }

    // col sums (symmetric contribution): reduce across quads (rows), skip on diagonal
    if (!diag) {
        #pragma unroll
        for (int ni = 0; ni < 4; ++ni) {
            float v = csum[ni];
            v += __shfl_xor(v, 16, 64);
            v += __shfl_xor(v, 32, 64);
            if (q == 0)
                atomicAdd(&row_s[c0 + wn + ni * 16 + l15], v);
        }
    }

    // ---- last block finalizes the loss ----
    __shared__ int lastflag;
    __shared__ float red[4];
    __syncthreads();   // all waves' atomics issued & drained (barrier waits vmcnt)
    if (tid == 0) {
        __threadfence();
        const int old = __hip_atomic_fetch_add(done, 1, __ATOMIC_ACQ_REL,
                                               __HIP_MEMORY_SCOPE_AGENT);
        lastflag = (old == NTILE - 1);
    }
    __syncthreads();
    if (!lastflag) return;

    float local = 0.0f;
    for (int i = tid; i < 8192; i += 256) {
        const float s = __hip_atomic_load(&row_s[i], __ATOMIC_RELAXED,
                                          __HIP_MEMORY_SCOPE_AGENT);
        const float p = __hip_atomic_load(&pos_out[i], __ATOMIC_RELAXED,
                                          __HIP_MEMORY_SCOPE_AGENT);
        local += __logf(s) - p;
    }
    #pragma unroll
    for (int off = 32; off > 0; off >>= 1) local += __shfl_xor(local, off, 64);
    if ((tid & 63) == 0) red[tid >> 6] = local;
    __syncthreads();
    if (tid == 0)
        out[0] = (red[0] + red[1] + red[2] + red[3]) * (1.0f / 8192.0f);
}

// ---------------- Launch ----------------
extern "C" void kernel_launch(void* const* d_in, const int* in_sizes, int n_in,
                              void* d_out, int out_size, void* d_ws, size_t ws_size,
                              hipStream_t stream)
{
    const float* zi = (const float*)d_in[0];
    const float* zj = (const float*)d_in[1];

    ushort* pn   = (ushort*)d_ws;                                    // 4 MB bf16 normalized rows
    float* row_s = (float*)((char*)d_ws + (4u << 20));               // 8192 fp32
    float* pos   = (float*)((char*)d_ws + (4u << 20) + (32u << 10)); // 8192 fp32
    int*   done  = (int*)((char*)d_ws + (4u << 20) + (64u << 10));   // counter
    float* out   = (float*)d_out;

    hipLaunchKernelGGL(normalize_bf16_kernel, dim3(2048), dim3(256), 0, stream,
                       zi, zj, pn, row_s, done);
    hipLaunchKernelGGL(simexp_kernel, dim3(NTILE), dim3(256), 0, stream,
                       pn, row_s, pos, done, out);
}

// Round 6
// 113.503 us; speedup vs baseline: 1.8272x; 1.8272x over previous
//
#include <hip/hip_runtime.h>
#include <hip/hip_bf16.h>
#include <stdint.h>

typedef short s16x8 __attribute__((ext_vector_type(8)));
typedef float f32x4 __attribute__((ext_vector_type(4)));

static constexpr int DDIM = 256;
static constexpr float TEN_LOG2E = 14.4269504088896340736f; // 10 * log2(e)

// ---------------- Kernel 1: normalize + pack into MFMA-fragment order ----------------
// 512 blocks x 256 threads; block g handles rows [16g, 16g+16). Output layout:
// packed[((g*8 + kt)*64 + lane)*8 .. +8] = bf16 P[16g + (lane&15)][kt*32 + (lane>>4)*8 ..]
// i.e. each (group, kt) fragment is one contiguous 1KB block in exact lane order, so a
// wave's A/B fragment load in kernel 2 is a single coalesced 16B/lane segment.
// Also zero-inits row_s[8192] (blocks 0..7) and out[0] (block 0).
__global__ __launch_bounds__(256) void normalize_pack_kernel(
    const float* __restrict__ zi, const float* __restrict__ zj,
    ushort* __restrict__ packed, float* __restrict__ row_s, float* __restrict__ out)
{
    __shared__ ushort lds[16 * 256];

    if (blockIdx.x < 8) {
        ((float4*)row_s)[blockIdx.x * 256 + threadIdx.x] = (float4){0.f, 0.f, 0.f, 0.f};
        if (blockIdx.x == 0 && threadIdx.x == 0) out[0] = 0.0f;
    }

    const int t = threadIdx.x;
    const int r = t >> 4;            // 0..15: row within group
    const int c = t & 15;            // 16 threads per row
    const int row = blockIdx.x * 16 + r;
    const float* src = (row < 4096) ? (zi + (size_t)row * DDIM)
                                    : (zj + (size_t)(row - 4096) * DDIM);
    float4 v[4];
    #pragma unroll
    for (int j = 0; j < 4; ++j) v[j] = ((const float4*)src)[c + j * 16];

    float ss = 0.0f;
    #pragma unroll
    for (int j = 0; j < 4; ++j)
        ss += v[j].x * v[j].x + v[j].y * v[j].y + v[j].z * v[j].z + v[j].w * v[j].w;
    // reduce across the 16 lanes of this row (lanes of a row are contiguous)
    ss += __shfl_xor(ss, 1, 64);
    ss += __shfl_xor(ss, 2, 64);
    ss += __shfl_xor(ss, 4, 64);
    ss += __shfl_xor(ss, 8, 64);
    const float inv = 1.0f / fmaxf(sqrtf(ss), 1e-8f);

    #pragma unroll
    for (int j = 0; j < 4; ++j) {
        ushort4 o;
        o.x = __builtin_bit_cast(unsigned short, __float2bfloat16(v[j].x * inv));
        o.y = __builtin_bit_cast(unsigned short, __float2bfloat16(v[j].y * inv));
        o.z = __builtin_bit_cast(unsigned short, __float2bfloat16(v[j].z * inv));
        o.w = __builtin_bit_cast(unsigned short, __float2bfloat16(v[j].w * inv));
        *(ushort4*)(lds + r * 256 + (c + j * 16) * 4) = o;
    }
    __syncthreads();

    // repack: 8 kt x 64 lanes = 512 fragment-slots of 16B per block; 2 per thread
    #pragma unroll
    for (int h = 0; h < 2; ++h) {
        const int idx  = h * 256 + t;
        const int kt   = idx >> 6;
        const int lane = idx & 63;
        const int q    = lane >> 4;
        const int l15  = lane & 15;
        s16x8 frag = *(const s16x8*)(lds + l15 * 256 + kt * 32 + q * 8);
        ((s16x8*)packed)[(size_t)(blockIdx.x * 8 + kt) * 64 + lane] = frag;
    }
}

// ---------------- Kernel 2: upper-triangle Gram tiles, coalesced fragment loads ------
// 2080 blocks = 64*65/2 tiles of 128x128; 4 waves x (64x64 via 16x16x32 MFMA, 4x4
// frags). No LDS, no barriers: fragments come straight from the packed (fragment-order)
// array — each load is one contiguous 1KB coalesced segment, L2-resident.
__global__ __launch_bounds__(256) void simexp_kernel(
    const ushort* __restrict__ packed,
    float* __restrict__ row_s,
    float* __restrict__ pos_out)
{
    const int tid  = threadIdx.x;
    const int w    = tid >> 6;
    const int lane = tid & 63;
    const int q    = lane >> 4;      // 0..3: K-octet of the MFMA operand
    const int l15  = lane & 15;
    const int wm   = (w >> 1) * 64;  // wave row offset in 128x128 tile
    const int wn   = (w & 1) * 64;   // wave col offset

    // ---- upper-triangle decode: block b -> (ti, tj), ti <= tj ----
    const int b = blockIdx.x;
    int ti = (int)(64.5f - sqrtf(64.5f * 64.5f - 2.0f * (float)b));
    while ((ti + 1) * 64 - ((ti + 1) * ti) / 2 <= b) ++ti;
    while (ti * 64 - (ti * (ti - 1)) / 2 > b) --ti;
    const int tj = ti + (b - (ti * 64 - (ti * (ti - 1)) / 2));
    const int r0 = ti * 128, c0 = tj * 128;
    const bool diag  = (ti == tj);
    const bool ptile = (tj == ti + 32);  // contains positive-pair diagonal

    // fragment base pointers into packed: group stride 4096 ushorts (8 kt x 1KB),
    // kt stride 512 ushorts (1KB)
    const int gA = (r0 + wm) >> 4;
    const int gB = (c0 + wn) >> 4;
    const ushort* pa[4];
    const ushort* pb[4];
    #pragma unroll
    for (int mi = 0; mi < 4; ++mi)
        pa[mi] = packed + (size_t)(gA + mi) * 4096 + (size_t)lane * 8;
    #pragma unroll
    for (int ni = 0; ni < 4; ++ni)
        pb[ni] = packed + (size_t)(gB + ni) * 4096 + (size_t)lane * 8;

    f32x4 acc[4][4];
    #pragma unroll
    for (int mi = 0; mi < 4; ++mi)
        #pragma unroll
        for (int ni = 0; ni < 4; ++ni)
            acc[mi][ni] = (f32x4){0.f, 0.f, 0.f, 0.f};

    #pragma unroll
    for (int kt = 0; kt < 8; ++kt) {
        s16x8 af[4], bfr[4];
        #pragma unroll
        for (int mi = 0; mi < 4; ++mi)
            af[mi] = *(const s16x8*)(pa[mi] + kt * 512);
        #pragma unroll
        for (int ni = 0; ni < 4; ++ni)
            bfr[ni] = *(const s16x8*)(pb[ni] + kt * 512);

        #pragma unroll
        for (int mi = 0; mi < 4; ++mi)
            #pragma unroll
            for (int ni = 0; ni < 4; ++ni)
                acc[mi][ni] = __builtin_amdgcn_mfma_f32_16x16x32_bf16(
                    af[mi], bfr[ni], acc[mi][ni], 0, 0, 0);
    }

    // ---- epilogue: exp, diag mask, positive extraction, row+col sums ----
    // C/D layout (16x16): col = lane&15, row = q*4 + r
    float rsum[4][4];
    float csum[4] = {0.f, 0.f, 0.f, 0.f};
    #pragma unroll
    for (int mi = 0; mi < 4; ++mi)
        #pragma unroll
        for (int r = 0; r < 4; ++r) rsum[mi][r] = 0.0f;

    #pragma unroll
    for (int mi = 0; mi < 4; ++mi)
        #pragma unroll
        for (int ni = 0; ni < 4; ++ni)
            #pragma unroll
            for (int r = 0; r < 4; ++r) {
                const int lr = wm + mi * 16 + q * 4 + r;
                const int lc = wn + ni * 16 + l15;
                float e = exp2f(acc[mi][ni][r] * TEN_LOG2E);
                if (diag && lr == lc) e = 0.0f;          // mask self-similarity
                rsum[mi][r] += e;
                csum[ni]    += e;
                if (ptile && lr == lc) {                 // positive pair: col = row + 4096
                    const float v = acc[mi][ni][r] * 10.0f;
                    pos_out[r0 + lr] = v;
                    pos_out[c0 + lr] = v;
                }
            }

    // row sums: reduce across the 16 lanes (cols) of each quad
    #pragma unroll
    for (int mi = 0; mi < 4; ++mi)
        #pragma unroll
        for (int r = 0; r < 4; ++r) {
            float v = rsum[mi][r];
            v += __shfl_xor(v, 1, 64);
            v += __shfl_xor(v, 2, 64);
            v += __shfl_xor(v, 4, 64);
            v += __shfl_xor(v, 8, 64);
            rsum[mi][r] = v;
        }
    if (l15 == 0) {
        #pragma unroll
        for (int mi = 0; mi < 4; ++mi)
            #pragma unroll
            for (int r = 0; r < 4; ++r)
                atomicAdd(&row_s[r0 + wm + mi * 16 + q * 4 + r], rsum[mi][r]);
    }

    // col sums (symmetric contribution): reduce across quads (rows), skip on diagonal
    if (!diag) {
        #pragma unroll
        for (int ni = 0; ni < 4; ++ni) {
            float v = csum[ni];
            v += __shfl_xor(v, 16, 64);
            v += __shfl_xor(v, 32, 64);
            if (q == 0)
                atomicAdd(&row_s[c0 + wn + ni * 16 + l15], v);
        }
    }
}

// ---------------- Kernel 3: finalize loss ----------------
__global__ __launch_bounds__(256) void finalize_kernel(
    const float* __restrict__ row_s, const float* __restrict__ pos,
    float* __restrict__ out)
{
    const int i = blockIdx.x * 256 + threadIdx.x;   // float4 index, 2048 total
    float4 s = ((const float4*)row_s)[i];
    float4 p = ((const float4*)pos)[i];
    float local = (__logf(s.x) - p.x) + (__logf(s.y) - p.y)
                + (__logf(s.z) - p.z) + (__logf(s.w) - p.w);
    #pragma unroll
    for (int off = 32; off > 0; off >>= 1) local += __shfl_xor(local, off, 64);
    __shared__ float red[4];
    if ((threadIdx.x & 63) == 0) red[threadIdx.x >> 6] = local;
    __syncthreads();
    if (threadIdx.x == 0)
        atomicAdd(out, (red[0] + red[1] + red[2] + red[3]) * (1.0f / 8192.0f));
}

// ---------------- Launch ----------------
extern "C" void kernel_launch(void* const* d_in, const int* in_sizes, int n_in,
                              void* d_out, int out_size, void* d_ws, size_t ws_size,
                              hipStream_t stream)
{
    const float* zi = (const float*)d_in[0];
    const float* zj = (const float*)d_in[1];

    ushort* packed = (ushort*)d_ws;                                    // 4 MB fragment-order bf16
    float* row_s   = (float*)((char*)d_ws + (4u << 20));               // 8192 fp32
    float* pos     = (float*)((char*)d_ws + (4u << 20) + (32u << 10)); // 8192 fp32
    float* out     = (float*)d_out;

    hipLaunchKernelGGL(normalize_pack_kernel, dim3(512), dim3(256), 0, stream,
                       zi, zj, packed, row_s, out);
    hipLaunchKernelGGL(simexp_kernel, dim3(2080), dim3(256), 0, stream,
                       packed, row_s, pos);
    hipLaunchKernelGGL(finalize_kernel, dim3(8), dim3(256), 0, stream, row_s, pos, out);
}